// Round 12
// baseline (446.183 us; speedup 1.0000x reference)
//
#include <hip/hip_runtime.h>
#include <stdint.h>

#define BS   8
#define CH   256    // C
#define LSEQ 4096   // H*W
#define DIN  256    // INNER
#define NT2  128    // number of KV tiles (32 rows each)
#define KT2  32     // kv rows per tile

typedef __bf16 bf16x8 __attribute__((ext_vector_type(8)));
typedef __bf16 bf16x4 __attribute__((ext_vector_type(4)));
typedef float  f32x4  __attribute__((ext_vector_type(4)));

// async global->LDS, 16B per lane; LDS dest = wave-uniform base + lane*16
__device__ __forceinline__ void gload_lds16(const void* g, void* l) {
    __builtin_amdgcn_global_load_lds(
        (const __attribute__((address_space(1))) uint32_t*)g,
        (__attribute__((address_space(3))) uint32_t*)l, 16, 0, 0);
}

#define CEXP_FOLD (1.4426950408889634f / 16.0f)   // log2(e)/round(sqrt(256),2)

// ---------------------------------------------------------------------------
// Kernel 1: QKV projection (R10's separate-kernel form — fused version
// regressed: 54KB LDS -> 2 blocks/CU exposed W-load latency).
// which==0 -> Q linear [l][i] bf16, PRE-SCALED by CEXP_FOLD.
// which==1 -> K swizzled image: tile(b,t2) 32KB, K half 16KB:
//             byte = row*512 + ((2i)^((row&7)<<4)), row = l&31.
// which==2 -> V FRAGMENT-MAJOR half at +16384 (NEW): vfrag[ds][lane][8 bf16],
//             lane = g*16+n16 holds V[kj=g*8+j][d=ds*16+n16] — each attn vf
//             load is one coalesced 1KB global_load_dwordx4, L1-resident.
// Tile stride 32KB; base = (b*128 + t2) << 15.
// ---------------------------------------------------------------------------
__global__ __launch_bounds__(256) void qkv_proj_kernel(
    const float* __restrict__ x,
    const float* __restrict__ Wq, const float* __restrict__ bq,
    const float* __restrict__ Wk, const float* __restrict__ bk,
    const float* __restrict__ Wv, const float* __restrict__ bv,
    __bf16* __restrict__ Q, uint8_t* __restrict__ KV)
{
    const int b     = blockIdx.z;
    const int which = blockIdx.y;
    const int l0    = blockIdx.x * 64;

    const float* W    = (which == 0) ? Wq : (which == 1) ? Wk : Wv;
    const float* bias = (which == 0) ? bq : (which == 1) ? bk : bv;
    const float* X    = x + (size_t)b * CH * LSEQ;

    __shared__ __align__(16) __bf16 sXt[64][40];   // [l][c]
    __shared__ __align__(16) __bf16 sW[256][40];   // [i][c]

    const int tid  = threadIdx.x;
    const int wv   = tid >> 6;
    const int lane = tid & 63;
    const int g    = lane >> 4;
    const int n16  = lane & 15;

    f32x4 acc[4][4];
    #pragma unroll
    for (int i = 0; i < 4; ++i)
        #pragma unroll
        for (int j = 0; j < 4; ++j)
            acc[i][j] = f32x4{0.f, 0.f, 0.f, 0.f};

    for (int kk = 0; kk < 8; ++kk) {
        const int c0 = kk * 32;
        __syncthreads();
        #pragma unroll
        for (int p = 0; p < 8; ++p) {
            const int i  = p * 32 + (tid >> 3);
            const int c4 = (tid & 7) * 4;
            const float4 v = *(const float4*)(W + (size_t)i * CH + c0 + c4);
            bf16x4 pk = { (__bf16)v.x, (__bf16)v.y, (__bf16)v.z, (__bf16)v.w };
            *(bf16x4*)&sW[i][c4] = pk;
        }
        #pragma unroll
        for (int p = 0; p < 2; ++p) {
            const int c  = p * 16 + (tid >> 4);
            const int l4 = (tid & 15) * 4;
            const float4 v = *(const float4*)(X + (size_t)(c0 + c) * LSEQ + l0 + l4);
            sXt[l4 + 0][c] = (__bf16)v.x;
            sXt[l4 + 1][c] = (__bf16)v.y;
            sXt[l4 + 2][c] = (__bf16)v.z;
            sXt[l4 + 3][c] = (__bf16)v.w;
        }
        __syncthreads();

        bf16x8 af[4], bfr[4];
        #pragma unroll
        for (int mr = 0; mr < 4; ++mr)
            af[mr] = *(const bf16x8*)&sXt[mr * 16 + n16][g * 8];
        #pragma unroll
        for (int nc = 0; nc < 4; ++nc)
            bfr[nc] = *(const bf16x8*)&sW[wv * 64 + nc * 16 + n16][g * 8];
        #pragma unroll
        for (int mr = 0; mr < 4; ++mr)
            #pragma unroll
            for (int nc = 0; nc < 4; ++nc)
                acc[mr][nc] = __builtin_amdgcn_mfma_f32_16x16x32_bf16(
                    af[mr], bfr[nc], acc[mr][nc], 0, 0, 0);
    }

    // D fragment: row l = mr*16 + g*4 + r, col i = nc*16 + n16 (+wv*64)
    if (which == 0) {
        __bf16* out = Q + (size_t)b * LSEQ * DIN;
        #pragma unroll
        for (int nc = 0; nc < 4; ++nc) {
            const int icol = wv * 64 + nc * 16 + n16;
            const float bb = bias[icol];
            #pragma unroll
            for (int mr = 0; mr < 4; ++mr) {
                const int lrow = l0 + mr * 16 + g * 4;
                #pragma unroll
                for (int r = 0; r < 4; ++r)
                    out[(size_t)(lrow + r) * DIN + icol] =
                        (__bf16)((acc[mr][nc][r] + bb) * CEXP_FOLD);
            }
        }
    } else if (which == 1) {
        #pragma unroll
        for (int nc = 0; nc < 4; ++nc) {
            const int icol = wv * 64 + nc * 16 + n16;
            const float bb = bias[icol];
            #pragma unroll
            for (int mr = 0; mr < 4; ++mr) {
                #pragma unroll
                for (int r = 0; r < 4; ++r) {
                    const int lrow = l0 + mr * 16 + g * 4 + r;
                    const int t2 = lrow >> 5, row = lrow & 31;
                    const size_t off = ((size_t)(b * NT2 + t2) << 15)
                                     + (size_t)row * 512
                                     + ((icol * 2) ^ ((row & 7) << 4));
                    *(__bf16*)(KV + off) = (__bf16)(acc[mr][nc][r] + bb);
                }
            }
        }
    } else {
        // V fragment-major: writer lane holds V[l][d]; kj = l&31.
        // kj = (mr&1)*16 + g*4 + r -> reader group gp = kj>>3 = (mr&1)*2 + (g>>1),
        // elem j = kj&7 = (g&1)*4 + r (4 consecutive r -> contiguous 8B).
        #pragma unroll
        for (int nc = 0; nc < 4; ++nc) {
            const int d  = wv * 64 + nc * 16 + n16;
            const float bb = bias[d];
            const int ds = d >> 4;         // = wv*4 + nc
            const int dn = d & 15;         // = n16
            #pragma unroll
            for (int mr = 0; mr < 4; ++mr) {
                const int lrow = l0 + mr * 16 + g * 4;
                const int t2 = lrow >> 5;
                const int gp = ((mr & 1) << 1) | (g >> 1);
                const int j0 = (g & 1) * 4;
                bf16x4 pk;
                #pragma unroll
                for (int r = 0; r < 4; ++r)
                    pk[r] = (__bf16)(acc[mr][nc][r] + bb);
                const size_t off = ((size_t)(b * NT2 + t2) << 15) + 16384
                                 + (size_t)ds * 1024
                                 + (size_t)(gp * 16 + dn) * 16 + j0 * 2;
                *(bf16x4*)(KV + off) = pk;
            }
        }
    }
}

// ---------------------------------------------------------------------------
// Kernel 2: flash attention v10 — R10 structure + V-direct-from-L1.
// All 4 waves (and both resident blocks) read byte-identical V fragments, so
// V skips LDS entirely: fragment-major global layout -> each vf is one
// coalesced 1KB global_load_dwordx4; 16KB/tile fits L1, 8 waves/CU hit it.
// LDS pipe/tile/CU: 332KB -> ~172KB (K reads + P + K staging writes);
// V's 128KB rides the parallel vector-memory pipe. K staging halves
// (16KB, vmcnt(4)). QK (swapped), softmax, defer-max, P path = R10 exact.
// Cliff rule: combined VGPR+AGPR <= ~196; vf loads kept in the PV loop so
// the compiler doesn't hoist 16x4 VGPRs of V.
// ---------------------------------------------------------------------------
__global__ __launch_bounds__(256) void attn_kernel(
    const __bf16* __restrict__ Q, const uint8_t* __restrict__ KV,
    __bf16* __restrict__ O)
{
    const int b   = blockIdx.x;
    const int q0  = blockIdx.y * 128 >> 1;   // = blockIdx.y * 64
    const int tid = threadIdx.x;
    const int wv  = tid >> 6, lane = tid & 63, g = lane >> 4, n16 = lane & 15;

    __shared__ __align__(1024) uint8_t sKV[2][16384];  // dbuf K tile images only
    __shared__ __align__(1024) uint8_t sP[4096];       // P [64 q][32 kj], pair-swizzled

    // Q fragments (pre-scaled): row q0 + wv*16 + n16; mfma B-operand (swapped QK)
    bf16x8 qf[8];
    {
        const __bf16* Qrow = Q + ((size_t)b * LSEQ + q0 + wv * 16 + n16) * DIN;
        #pragma unroll
        for (int ks = 0; ks < 8; ++ks)
            qf[ks] = *(const bf16x8*)(Qrow + ks * 32 + g * 8);
    }

    // constant ones B-fragment (layout-invariant for all-equal values)
    bf16x8 onesf;
    #pragma unroll
    for (int j = 0; j < 8; ++j) onesf[j] = (__bf16)1.0f;

    float m_i = -__builtin_inff();   // running max for q = q0+wv*16+n16 (log2 units)
    f32x4 accO[16];
    #pragma unroll
    for (int ds = 0; ds < 16; ++ds) accO[ds] = f32x4{0.f, 0.f, 0.f, 0.f};
    f32x4 accL = f32x4{0.f, 0.f, 0.f, 0.f};   // denominator, rows g*4+r

    const uint8_t* KVb = KV + ((size_t)b * NT2 << 15);
    const float DEFER_TH = 8.0f;   // log2 units: P bounded by 2^8

    // prologue: stage K tile 0 (256 thr x 16B x 4 = 16KB)
    #pragma unroll
    for (int p = 0; p < 4; ++p) {
        const int off = p * 4096 + tid * 16;
        gload_lds16(KVb + off, &sKV[0][off]);
    }

    // P-store addressing (row = q = wv*16 + n16, fixed per lane)
    const int prow  = wv * 16 + n16;
    const int pbase = (prow >> 1) * 128;
    const int pswz  = ((prow >> 1) & 7) << 4;
    const int phalf = (prow & 1) * 64;

    for (int t = 0; t < NT2; ++t) {
        const int buf = t & 1;
        if (t + 1 < NT2) {
            const uint8_t* src = KVb + ((size_t)(t + 1) << 15);
            #pragma unroll
            for (int p = 0; p < 4; ++p) {
                const int off = p * 4096 + tid * 16;
                gload_lds16(src + off, &sKV[buf ^ 1][off]);
            }
            asm volatile("s_waitcnt vmcnt(4)" ::: "memory");  // cur K done, next in flight
        } else {
            asm volatile("s_waitcnt vmcnt(0)" ::: "memory");
        }
        __builtin_amdgcn_s_barrier();
        asm volatile("" ::: "memory");

        const uint8_t* kb = sKV[buf];
        const __bf16* Vg = (const __bf16*)(KVb + ((size_t)t << 15) + 16384);

        // ---- S^T = K*Q^T : D[kj][q]; lane holds kj = {g*4+r, 16+g*4+r}, q = n16 ----
        f32x4 st0 = f32x4{0.f, 0.f, 0.f, 0.f};
        f32x4 st1 = f32x4{0.f, 0.f, 0.f, 0.f};
        __builtin_amdgcn_s_setprio(1);
        #pragma unroll
        for (int ks = 0; ks < 8; ++ks) {
            const int r0 = n16;          // kj rows 0-15
            const int r1 = 16 + n16;     // kj rows 16-31
            const bf16x8 kf0 = *(const bf16x8*)(kb + r0 * 512
                                + ((ks * 64 + g * 16) ^ ((r0 & 7) << 4)));
            const bf16x8 kf1 = *(const bf16x8*)(kb + r1 * 512
                                + ((ks * 64 + g * 16) ^ ((r1 & 7) << 4)));
            st0 = __builtin_amdgcn_mfma_f32_16x16x32_bf16(kf0, qf[ks], st0, 0, 0, 0);
            st1 = __builtin_amdgcn_mfma_f32_16x16x32_bf16(kf1, qf[ks], st1, 0, 0, 0);
        }
        __builtin_amdgcn_s_setprio(0);

        // ---- softmax for q = n16: 7 in-reg fmax + 2 shfl over g-groups ----
        float mx = fmaxf(fmaxf(fmaxf(st0[0], st0[1]), fmaxf(st0[2], st0[3])),
                         fmaxf(fmaxf(st1[0], st1[1]), fmaxf(st1[2], st1[3])));
        mx = fmaxf(mx, __shfl_xor(mx, 16));
        mx = fmaxf(mx, __shfl_xor(mx, 32));
        if (!__all(mx - m_i <= DEFER_TH)) {
            const float mnew = fmaxf(m_i, mx);
            const float scl  = exp2f(m_i - mnew);
            m_i = mnew;
            float sclr[4];
            #pragma unroll
            for (int r = 0; r < 4; ++r)
                sclr[r] = __shfl(scl, g * 4 + r);   // scl for acc rows q' = g*4+r
            #pragma unroll
            for (int ds = 0; ds < 16; ++ds)
                #pragma unroll
                for (int r = 0; r < 4; ++r)
                    accO[ds][r] *= sclr[r];
            #pragma unroll
            for (int r = 0; r < 4; ++r)
                accL[r] *= sclr[r];
        }

        // ---- P = exp2(S'-m); packed bf16x4 stores (2 ds_writes/lane) ----
        {
            bf16x4 pk0, pk1;
            #pragma unroll
            for (int r = 0; r < 4; ++r) {
                pk0[r] = (__bf16)exp2f(st0[r] - m_i);
                pk1[r] = (__bf16)exp2f(st1[r] - m_i);
            }
            const int c0b = 2 * (g * 4);          // kj cols g*4..g*4+3 (8B run)
            *(bf16x4*)(sP + pbase + ((phalf + c0b) ^ pswz))      = pk0;
            *(bf16x4*)(sP + pbase + ((phalf + c0b + 32) ^ pswz)) = pk1;  // +16 kj
        }

        // ---- PV: A = P row (n16) from LDS, B = V fragment from L1 ----
        bf16x8 af;
        {
            const int row = wv * 16 + n16;
            af = *(const bf16x8*)(sP + (row >> 1) * 128
                   + ((((row & 1) * 64) + g * 16) ^ (((row >> 1) & 7) << 4)));
        }
        __builtin_amdgcn_s_setprio(1);
        #pragma unroll
        for (int ds = 0; ds < 16; ++ds) {
            const bf16x8 vf = *(const bf16x8*)(Vg + ds * 512 + lane * 8);
            accO[ds] = __builtin_amdgcn_mfma_f32_16x16x32_bf16(af, vf, accO[ds], 0, 0, 0);
        }
        accL = __builtin_amdgcn_mfma_f32_16x16x32_bf16(af, onesf, accL, 0, 0, 0);
        __builtin_amdgcn_s_setprio(0);

        asm volatile("" ::: "memory");
        __builtin_amdgcn_s_barrier();   // all waves done reading K buf before overwrite
    }

    // ---- epilogue: O[l][d] = accO / accL (rows already aligned) ----
    float inv[4];
    #pragma unroll
    for (int r = 0; r < 4; ++r) inv[r] = 1.f / accL[r];
    __bf16* Ob = O + ((size_t)b * LSEQ + q0 + wv * 16) * DIN;
    #pragma unroll
    for (int ds = 0; ds < 16; ++ds)
        #pragma unroll
        for (int r = 0; r < 4; ++r)
            Ob[(size_t)(g * 4 + r) * DIN + ds * 16 + n16] = (__bf16)(accO[ds][r] * inv[r]);
}

// ---------------------------------------------------------------------------
// Kernel 3: output projection. out[b][c][l] = sum_i Wo[c][i]*O[b][l][i] + bo[c].
// ---------------------------------------------------------------------------
__global__ __launch_bounds__(256) void out_proj_kernel(
    const float* __restrict__ Wo, const float* __restrict__ bo,
    const __bf16* __restrict__ O, float* __restrict__ out)
{
    const int b   = blockIdx.z;
    const int c0  = blockIdx.y * 64;
    const int l0  = blockIdx.x * 256;
    const int tid = threadIdx.x;
    const int wv  = tid >> 6, lane = tid & 63, g = lane >> 4, n16 = lane & 15;

    __shared__ __align__(16) __bf16 sWo[64][40];   // [c][i]
    __shared__ __align__(16) __bf16 sO[256][40];   // [l][i]

    const __bf16* Ob = O + (size_t)b * LSEQ * DIN;

    f32x4 acc[4][4];
    #pragma unroll
    for (int i = 0; i < 4; ++i)
        #pragma unroll
        for (int j = 0; j < 4; ++j)
            acc[i][j] = f32x4{0.f, 0.f, 0.f, 0.f};

    for (int kk = 0; kk < 8; ++kk) {
        const int i0 = kk * 32;
        __syncthreads();
        #pragma unroll
        for (int p = 0; p < 2; ++p) {
            const int c  = p * 32 + (tid >> 3);
            const int i4 = (tid & 7) * 4;
            const float4 v = *(const float4*)(Wo + (size_t)(c0 + c) * DIN + i0 + i4);
            bf16x4 pk = { (__bf16)v.x, (__bf16)v.y, (__bf16)v.z, (__bf16)v.w };
            *(bf16x4*)&sWo[c][i4] = pk;
        }
        #pragma unroll
        for (int p = 0; p < 4; ++p) {
            const int l  = p * 64 + (tid >> 2);
            const int sg = tid & 3;
            *(uint4*)&sO[l][sg * 8] = *(const uint4*)(Ob + (size_t)(l0 + l) * DIN + i0 + sg * 8);
        }
        __syncthreads();

        bf16x8 af[4], bfr[4];
        #pragma unroll
        for (int mr = 0; mr < 4; ++mr)
            af[mr] = *(const bf16x8*)&sWo[mr * 16 + n16][g * 8];
        #pragma unroll
        for (int nc = 0; nc < 4; ++nc)
            bfr[nc] = *(const bf16x8*)&sO[wv * 64 + nc * 16 + n16][g * 8];
        #pragma unroll
        for (int mr = 0; mr < 4; ++mr)
            #pragma unroll
            for (int nc = 0; nc < 4; ++nc)
                acc[mr][nc] = __builtin_amdgcn_mfma_f32_16x16x32_bf16(
                    af[mr], bfr[nc], acc[mr][nc], 0, 0, 0);
    }

    #pragma unroll
    for (int mr = 0; mr < 4; ++mr) {
        const int c = c0 + mr * 16 + g * 4;
        #pragma unroll
        for (int nc = 0; nc < 4; ++nc) {
            const int l = l0 + wv * 64 + nc * 16 + n16;
            #pragma unroll
            for (int r = 0; r < 4; ++r)
                out[((size_t)b * CH + c + r) * LSEQ + l] = acc[mr][nc][r] + bo[c + r];
        }
    }
}

// ---------------------------------------------------------------------------
extern "C" void kernel_launch(void* const* d_in, const int* in_sizes, int n_in,
                              void* d_out, int out_size, void* d_ws, size_t ws_size,
                              hipStream_t stream)
{
    const float* x  = (const float*)d_in[0];
    const float* Wq = (const float*)d_in[1];
    const float* bq = (const float*)d_in[2];
    const float* Wk = (const float*)d_in[3];
    const float* bk = (const float*)d_in[4];
    const float* Wv = (const float*)d_in[5];
    const float* bv = (const float*)d_in[6];
    const float* Wo = (const float*)d_in[7];
    const float* bo = (const float*)d_in[8];
    float* out = (float*)d_out;

    // ws: Q bf16 16MB | KV tile images 32MB | O bf16 16MB = 64MB
    __bf16*  Q  = (__bf16*)d_ws;
    uint8_t* KV = (uint8_t*)d_ws + (16u << 20);
    __bf16*  O  = (__bf16*)((uint8_t*)d_ws + (48u << 20));

    qkv_proj_kernel<<<dim3(LSEQ / 64, 3, BS), 256, 0, stream>>>(
        x, Wq, bq, Wk, bk, Wv, bv, Q, KV);
    attn_kernel<<<dim3(BS, LSEQ / 64), 256, 0, stream>>>(Q, KV, O);
    out_proj_kernel<<<dim3(LSEQ / 256, CH / 64, BS), 256, 0, stream>>>(Wo, bo, O, out);
}

// Round 13
// 262.242 us; speedup vs baseline: 1.7014x; 1.7014x over previous
//
#include <hip/hip_runtime.h>
#include <stdint.h>

#define BS   8
#define CH   256    // C
#define LSEQ 4096   // H*W
#define DIN  256    // INNER
#define NT2  128    // number of KV tiles (32 rows each)
#define KT2  32     // kv rows per tile

typedef __bf16 bf16x8 __attribute__((ext_vector_type(8)));
typedef __bf16 bf16x4 __attribute__((ext_vector_type(4)));
typedef float  f32x4  __attribute__((ext_vector_type(4)));

// async global->LDS, 16B per lane; LDS dest = wave-uniform base + lane*16
__device__ __forceinline__ void gload_lds16(const void* g, void* l) {
    __builtin_amdgcn_global_load_lds(
        (const __attribute__((address_space(1))) uint32_t*)g,
        (__attribute__((address_space(3))) uint32_t*)l, 16, 0, 0);
}

#define CEXP_FOLD (1.4426950408889634f / 16.0f)   // log2(e)/round(sqrt(256),2)

// ---------------------------------------------------------------------------
// Kernel 1: QKV projection. Y[l][i] = sum_c X[c][l]*W[i][c] + b[i].
// which==0 -> Q linear [l][i] bf16, PRE-SCALED by CEXP_FOLD (log2-folded
//             softmax scale; attn computes exp2(S'-m') directly).
// which==1 -> K into swizzled tile image: tile(b,t2) 32KB, K half 16KB:
//             byte = row*512 + ((2i) ^ ((row&7)<<4)), row = l&31.
// which==2 -> V half at +16384: d-pair rows of 128B:
//             byte = 16384 + (d>>1)*128 + (((d&1)*64 + 2*(l&31)) ^ (((d>>1)&7)<<4)).
// Tile stride 32KB; base = (b*128 + t2) << 15.
// ---------------------------------------------------------------------------
__global__ __launch_bounds__(256) void qkv_proj_kernel(
    const float* __restrict__ x,
    const float* __restrict__ Wq, const float* __restrict__ bq,
    const float* __restrict__ Wk, const float* __restrict__ bk,
    const float* __restrict__ Wv, const float* __restrict__ bv,
    __bf16* __restrict__ Q, uint8_t* __restrict__ KV)
{
    const int b     = blockIdx.z;
    const int which = blockIdx.y;
    const int l0    = blockIdx.x * 64;

    const float* W    = (which == 0) ? Wq : (which == 1) ? Wk : Wv;
    const float* bias = (which == 0) ? bq : (which == 1) ? bk : bv;
    const float* X    = x + (size_t)b * CH * LSEQ;

    __shared__ __align__(16) __bf16 sXt[64][40];   // [l][c]
    __shared__ __align__(16) __bf16 sW[256][40];   // [i][c]

    const int tid  = threadIdx.x;
    const int wv   = tid >> 6;
    const int lane = tid & 63;
    const int g    = lane >> 4;
    const int n16  = lane & 15;

    f32x4 acc[4][4];
    #pragma unroll
    for (int i = 0; i < 4; ++i)
        #pragma unroll
        for (int j = 0; j < 4; ++j)
            acc[i][j] = f32x4{0.f, 0.f, 0.f, 0.f};

    for (int kk = 0; kk < 8; ++kk) {
        const int c0 = kk * 32;
        __syncthreads();
        #pragma unroll
        for (int p = 0; p < 8; ++p) {
            const int i  = p * 32 + (tid >> 3);
            const int c4 = (tid & 7) * 4;
            const float4 v = *(const float4*)(W + (size_t)i * CH + c0 + c4);
            bf16x4 pk = { (__bf16)v.x, (__bf16)v.y, (__bf16)v.z, (__bf16)v.w };
            *(bf16x4*)&sW[i][c4] = pk;
        }
        #pragma unroll
        for (int p = 0; p < 2; ++p) {
            const int c  = p * 16 + (tid >> 4);
            const int l4 = (tid & 15) * 4;
            const float4 v = *(const float4*)(X + (size_t)(c0 + c) * LSEQ + l0 + l4);
            sXt[l4 + 0][c] = (__bf16)v.x;
            sXt[l4 + 1][c] = (__bf16)v.y;
            sXt[l4 + 2][c] = (__bf16)v.z;
            sXt[l4 + 3][c] = (__bf16)v.w;
        }
        __syncthreads();

        bf16x8 af[4], bfr[4];
        #pragma unroll
        for (int mr = 0; mr < 4; ++mr)
            af[mr] = *(const bf16x8*)&sXt[mr * 16 + n16][g * 8];
        #pragma unroll
        for (int nc = 0; nc < 4; ++nc)
            bfr[nc] = *(const bf16x8*)&sW[wv * 64 + nc * 16 + n16][g * 8];
        #pragma unroll
        for (int mr = 0; mr < 4; ++mr)
            #pragma unroll
            for (int nc = 0; nc < 4; ++nc)
                acc[mr][nc] = __builtin_amdgcn_mfma_f32_16x16x32_bf16(
                    af[mr], bfr[nc], acc[mr][nc], 0, 0, 0);
    }

    // D fragment: row l = mr*16 + g*4 + r, col i = nc*16 + n16 (+wv*64)
    if (which == 0) {
        __bf16* out = Q + (size_t)b * LSEQ * DIN;
        #pragma unroll
        for (int nc = 0; nc < 4; ++nc) {
            const int icol = wv * 64 + nc * 16 + n16;
            const float bb = bias[icol];
            #pragma unroll
            for (int mr = 0; mr < 4; ++mr) {
                const int lrow = l0 + mr * 16 + g * 4;
                #pragma unroll
                for (int r = 0; r < 4; ++r)
                    out[(size_t)(lrow + r) * DIN + icol] =
                        (__bf16)((acc[mr][nc][r] + bb) * CEXP_FOLD);
            }
        }
    } else if (which == 1) {
        #pragma unroll
        for (int nc = 0; nc < 4; ++nc) {
            const int icol = wv * 64 + nc * 16 + n16;
            const float bb = bias[icol];
            #pragma unroll
            for (int mr = 0; mr < 4; ++mr) {
                #pragma unroll
                for (int r = 0; r < 4; ++r) {
                    const int lrow = l0 + mr * 16 + g * 4 + r;
                    const int t2 = lrow >> 5, row = lrow & 31;
                    const size_t off = ((size_t)(b * NT2 + t2) << 15)
                                     + (size_t)row * 512
                                     + ((icol * 2) ^ ((row & 7) << 4));
                    *(__bf16*)(KV + off) = (__bf16)(acc[mr][nc][r] + bb);
                }
            }
        }
    } else {
        #pragma unroll
        for (int nc = 0; nc < 4; ++nc) {
            const int d  = wv * 64 + nc * 16 + n16;
            const float bb = bias[d];
            #pragma unroll
            for (int mr = 0; mr < 4; ++mr) {
                const int lrow = l0 + mr * 16 + g * 4;   // 4 consecutive l (8B run)
                const int t2 = lrow >> 5, c = lrow & 31;
                bf16x4 pk;
                #pragma unroll
                for (int r = 0; r < 4; ++r)
                    pk[r] = (__bf16)(acc[mr][nc][r] + bb);
                const size_t off = ((size_t)(b * NT2 + t2) << 15) + 16384
                                 + (size_t)(d >> 1) * 128
                                 + ((((d & 1) * 64) + 2 * c) ^ (((d >> 1) & 7) << 4));
                *(bf16x4*)(KV + off) = pk;
            }
        }
    }
}

// ---------------------------------------------------------------------------
// Kernel 2: flash attention v8 (R10 — best measured: attn 225us, total 263us).
// 4 waves x 16 q-rows; KV tile 32 rows; dbuf pre-swizzled images staged via
// global_load_lds + counted vmcnt; 2 INDEPENDENT blocks/CU (de-lockstep TLP).
// Swapped QK^T (st = mfma(kf, qf)): lane n16 owns a full q-column -> softmax
// max = 7 in-reg fmax + 2 shfl; m_i one scalar. Packed bf16x4 P-stores.
// Denominator via ones-MFMA accL (epilogue row-aligned). Defer-max TH=8.
// Cliff rule: combined VGPR+AGPR <= ~196 (here ~192: 124 VGPR + 68 AGPR).
// LDS traffic model: 332KB/tile/CU at 85 B/cyc = ~95% of measured cycles ->
// LDS-pipe-bound; q-rows/wave (the only byte reducer) is register-capped.
// ---------------------------------------------------------------------------
__global__ __launch_bounds__(256) void attn_kernel(
    const __bf16* __restrict__ Q, const uint8_t* __restrict__ KV,
    __bf16* __restrict__ O)
{
    const int b   = blockIdx.x;
    const int q0  = blockIdx.y * 64;
    const int tid = threadIdx.x;
    const int wv  = tid >> 6, lane = tid & 63, g = lane >> 4, n16 = lane & 15;

    __shared__ __align__(1024) uint8_t sKV[2][32768];  // dbuf 32-row KV tiles
    __shared__ __align__(1024) uint8_t sP[4096];       // P [64 q][32 kj], pair-swizzled

    // Q fragments (pre-scaled): row q0 + wv*16 + n16; used as mfma B-operand
    bf16x8 qf[8];
    {
        const __bf16* Qrow = Q + ((size_t)b * LSEQ + q0 + wv * 16 + n16) * DIN;
        #pragma unroll
        for (int ks = 0; ks < 8; ++ks)
            qf[ks] = *(const bf16x8*)(Qrow + ks * 32 + g * 8);
    }

    // constant ones B-fragment (layout-invariant for all-equal values)
    bf16x8 onesf;
    #pragma unroll
    for (int j = 0; j < 8; ++j) onesf[j] = (__bf16)1.0f;

    float m_i = -__builtin_inff();   // running max for q = q0+wv*16+n16 (log2 units)
    f32x4 accO[16];
    #pragma unroll
    for (int ds = 0; ds < 16; ++ds) accO[ds] = f32x4{0.f, 0.f, 0.f, 0.f};
    f32x4 accL = f32x4{0.f, 0.f, 0.f, 0.f};   // denominator, rows g*4+r

    const uint8_t* KVb = KV + ((size_t)b * NT2 << 15);
    const float DEFER_TH = 8.0f;   // log2 units: P bounded by 2^8

    // prologue: stage tile 0 (256 thr x 16B x 8 = 32KB)
    #pragma unroll
    for (int p = 0; p < 8; ++p) {
        const int off = p * 4096 + tid * 16;
        gload_lds16(KVb + off, &sKV[0][off]);
    }

    // P-store addressing (row = q = wv*16 + n16, fixed per lane):
    const int prow  = wv * 16 + n16;
    const int pbase = (prow >> 1) * 128;
    const int pswz  = ((prow >> 1) & 7) << 4;
    const int phalf = (prow & 1) * 64;

    for (int t = 0; t < NT2; ++t) {
        const int buf = t & 1;
        if (t + 1 < NT2) {
            const uint8_t* src = KVb + ((size_t)(t + 1) << 15);
            #pragma unroll
            for (int p = 0; p < 8; ++p) {
                const int off = p * 4096 + tid * 16;
                gload_lds16(src + off, &sKV[buf ^ 1][off]);
            }
            asm volatile("s_waitcnt vmcnt(8)" ::: "memory");  // cur tile done, next in flight
        } else {
            asm volatile("s_waitcnt vmcnt(0)" ::: "memory");
        }
        __builtin_amdgcn_s_barrier();
        asm volatile("" ::: "memory");

        const uint8_t* kb = sKV[buf];

        // ---- S^T = K*Q^T : D[kj][q]; lane holds kj = {g*4+r, 16+g*4+r}, q = n16 ----
        f32x4 st0 = f32x4{0.f, 0.f, 0.f, 0.f};
        f32x4 st1 = f32x4{0.f, 0.f, 0.f, 0.f};
        __builtin_amdgcn_s_setprio(1);
        #pragma unroll
        for (int ks = 0; ks < 8; ++ks) {
            const int r0 = n16;          // kj rows 0-15
            const int r1 = 16 + n16;     // kj rows 16-31
            const bf16x8 kf0 = *(const bf16x8*)(kb + r0 * 512
                                + ((ks * 64 + g * 16) ^ ((r0 & 7) << 4)));
            const bf16x8 kf1 = *(const bf16x8*)(kb + r1 * 512
                                + ((ks * 64 + g * 16) ^ ((r1 & 7) << 4)));
            st0 = __builtin_amdgcn_mfma_f32_16x16x32_bf16(kf0, qf[ks], st0, 0, 0, 0);
            st1 = __builtin_amdgcn_mfma_f32_16x16x32_bf16(kf1, qf[ks], st1, 0, 0, 0);
        }
        __builtin_amdgcn_s_setprio(0);

        // ---- softmax for q = n16: 7 in-reg fmax + 2 shfl over g-groups ----
        float mx = fmaxf(fmaxf(fmaxf(st0[0], st0[1]), fmaxf(st0[2], st0[3])),
                         fmaxf(fmaxf(st1[0], st1[1]), fmaxf(st1[2], st1[3])));
        mx = fmaxf(mx, __shfl_xor(mx, 16));
        mx = fmaxf(mx, __shfl_xor(mx, 32));
        if (!__all(mx - m_i <= DEFER_TH)) {
            const float mnew = fmaxf(m_i, mx);
            const float scl  = exp2f(m_i - mnew);
            m_i = mnew;
            float sclr[4];
            #pragma unroll
            for (int r = 0; r < 4; ++r)
                sclr[r] = __shfl(scl, g * 4 + r);   // scl for acc rows q' = g*4+r
            #pragma unroll
            for (int ds = 0; ds < 16; ++ds)
                #pragma unroll
                for (int r = 0; r < 4; ++r)
                    accO[ds][r] *= sclr[r];
            #pragma unroll
            for (int r = 0; r < 4; ++r)
                accL[r] *= sclr[r];
        }

        // ---- P = exp2(S'-m); packed bf16x4 stores (2 ds_writes/lane) ----
        {
            bf16x4 pk0, pk1;
            #pragma unroll
            for (int r = 0; r < 4; ++r) {
                pk0[r] = (__bf16)exp2f(st0[r] - m_i);
                pk1[r] = (__bf16)exp2f(st1[r] - m_i);
            }
            const int c0b = 2 * (g * 4);          // kj cols g*4..g*4+3 (8B run)
            *(bf16x4*)(sP + pbase + ((phalf + c0b) ^ pswz))      = pk0;
            *(bf16x4*)(sP + pbase + ((phalf + c0b + 32) ^ pswz)) = pk1;  // +16 kj
        }

        // ---- PV: A = P row (n16), B = V pair-swizzled img; +ones-MFMA for l ----
        bf16x8 af;
        {
            const int row = wv * 16 + n16;
            af = *(const bf16x8*)(sP + (row >> 1) * 128
                   + ((((row & 1) * 64) + g * 16) ^ (((row >> 1) & 7) << 4)));
        }
        __builtin_amdgcn_s_setprio(1);
        #pragma unroll
        for (int ds = 0; ds < 16; ++ds) {
            const int d = ds * 16 + n16;
            const bf16x8 vf = *(const bf16x8*)(kb + 16384 + (d >> 1) * 128
                               + ((((d & 1) * 64) + g * 16) ^ (((d >> 1) & 7) << 4)));
            accO[ds] = __builtin_amdgcn_mfma_f32_16x16x32_bf16(af, vf, accO[ds], 0, 0, 0);
        }
        accL = __builtin_amdgcn_mfma_f32_16x16x32_bf16(af, onesf, accL, 0, 0, 0);
        __builtin_amdgcn_s_setprio(0);

        asm volatile("" ::: "memory");
        __builtin_amdgcn_s_barrier();   // all waves done reading buf before overwrite
    }

    // ---- epilogue: O[l][d] = accO / accL (rows already aligned) ----
    float inv[4];
    #pragma unroll
    for (int r = 0; r < 4; ++r) inv[r] = 1.f / accL[r];
    __bf16* Ob = O + ((size_t)b * LSEQ + q0 + wv * 16) * DIN;
    #pragma unroll
    for (int ds = 0; ds < 16; ++ds)
        #pragma unroll
        for (int r = 0; r < 4; ++r)
            Ob[(size_t)(g * 4 + r) * DIN + ds * 16 + n16] = (__bf16)(accO[ds][r] * inv[r]);
}

// ---------------------------------------------------------------------------
// Kernel 3: output projection. out[b][c][l] = sum_i Wo[c][i]*O[b][l][i] + bo[c].
// ---------------------------------------------------------------------------
__global__ __launch_bounds__(256) void out_proj_kernel(
    const float* __restrict__ Wo, const float* __restrict__ bo,
    const __bf16* __restrict__ O, float* __restrict__ out)
{
    const int b   = blockIdx.z;
    const int c0  = blockIdx.y * 64;
    const int l0  = blockIdx.x * 256;
    const int tid = threadIdx.x;
    const int wv  = tid >> 6, lane = tid & 63, g = lane >> 4, n16 = lane & 15;

    __shared__ __align__(16) __bf16 sWo[64][40];   // [c][i]
    __shared__ __align__(16) __bf16 sO[256][40];   // [l][i]

    const __bf16* Ob = O + (size_t)b * LSEQ * DIN;

    f32x4 acc[4][4];
    #pragma unroll
    for (int i = 0; i < 4; ++i)
        #pragma unroll
        for (int j = 0; j < 4; ++j)
            acc[i][j] = f32x4{0.f, 0.f, 0.f, 0.f};

    for (int kk = 0; kk < 8; ++kk) {
        const int i0 = kk * 32;
        __syncthreads();
        #pragma unroll
        for (int p = 0; p < 2; ++p) {
            const int c  = p * 32 + (tid >> 3);
            const int i4 = (tid & 7) * 4;
            const float4 v = *(const float4*)(Wo + (size_t)(c0 + c) * DIN + i0 + i4);
            bf16x4 pk = { (__bf16)v.x, (__bf16)v.y, (__bf16)v.z, (__bf16)v.w };
            *(bf16x4*)&sWo[c][i4] = pk;
        }
        #pragma unroll
        for (int p = 0; p < 4; ++p) {
            const int l  = p * 64 + (tid >> 2);
            const int sg = tid & 3;
            *(uint4*)&sO[l][sg * 8] = *(const uint4*)(Ob + (size_t)(l0 + l) * DIN + i0 + sg * 8);
        }
        __syncthreads();

        bf16x8 af[4], bfr[4];
        #pragma unroll
        for (int mr = 0; mr < 4; ++mr)
            af[mr] = *(const bf16x8*)&sWo[mr * 16 + n16][g * 8];
        #pragma unroll
        for (int nc = 0; nc < 4; ++nc)
            bfr[nc] = *(const bf16x8*)&sO[wv * 64 + nc * 16 + n16][g * 8];
        #pragma unroll
        for (int mr = 0; mr < 4; ++mr)
            #pragma unroll
            for (int nc = 0; nc < 4; ++nc)
                acc[mr][nc] = __builtin_amdgcn_mfma_f32_16x16x32_bf16(
                    af[mr], bfr[nc], acc[mr][nc], 0, 0, 0);
    }

    #pragma unroll
    for (int mr = 0; mr < 4; ++mr) {
        const int c = c0 + mr * 16 + g * 4;
        #pragma unroll
        for (int nc = 0; nc < 4; ++nc) {
            const int l = l0 + wv * 64 + nc * 16 + n16;
            #pragma unroll
            for (int r = 0; r < 4; ++r)
                out[((size_t)b * CH + c + r) * LSEQ + l] = acc[mr][nc][r] + bo[c + r];
        }
    }
}

// ---------------------------------------------------------------------------
extern "C" void kernel_launch(void* const* d_in, const int* in_sizes, int n_in,
                              void* d_out, int out_size, void* d_ws, size_t ws_size,
                              hipStream_t stream)
{
    const float* x  = (const float*)d_in[0];
    const float* Wq = (const float*)d_in[1];
    const float* bq = (const float*)d_in[2];
    const float* Wk = (const float*)d_in[3];
    const float* bk = (const float*)d_in[4];
    const float* Wv = (const float*)d_in[5];
    const float* bv = (const float*)d_in[6];
    const float* Wo = (const float*)d_in[7];
    const float* bo = (const float*)d_in[8];
    float* out = (float*)d_out;

    // ws: Q bf16 16MB | KV swizzled tile images 32MB | O bf16 16MB = 64MB
    __bf16*  Q  = (__bf16*)d_ws;
    uint8_t* KV = (uint8_t*)d_ws + (16u << 20);
    __bf16*  O  = (__bf16*)((uint8_t*)d_ws + (48u << 20));

    qkv_proj_kernel<<<dim3(LSEQ / 64, 3, BS), 256, 0, stream>>>(
        x, Wq, bq, Wk, bk, Wv, bv, Q, KV);
    attn_kernel<<<dim3(BS, LSEQ / 64), 256, 0, stream>>>(Q, KV, O);
    out_proj_kernel<<<dim3(LSEQ / 256, CH / 64, BS), 256, 0, stream>>>(Wo, bo, O, out);
}